// Round 7
// baseline (70.784 us; speedup 1.0000x reference)
//
#include <hip/hip_runtime.h>
#include <hip/hip_bf16.h>

#define EMBED   1024
#define NHEADS  16
#define HDIM    64
#define BATCH   2
#define SEQ     2048
#define KSPLIT  4
#define LOG2E   1.44269504088896340736f

typedef __attribute__((ext_vector_type(8))) short bf16x8;
typedef __attribute__((ext_vector_type(4))) short bf16x4;
typedef __attribute__((ext_vector_type(4))) float f32x4;
typedef __attribute__((ext_vector_type(16))) float f32x16;
using bf16 = __hip_bfloat16;

__device__ __forceinline__ float fast_exp2(float x) {
    float r; asm("v_exp_f32 %0, %1" : "=v"(r) : "v"(x)); return r;
}

// async global->LDS, 16B per lane; LDS dest is wave-uniform base + lane*16
__device__ __forceinline__ void gload_lds16(const bf16* g, bf16* l) {
    __builtin_amdgcn_global_load_lds(
        (const __attribute__((address_space(1))) void*)g,
        (__attribute__((address_space(3))) void*)l, 16, 0, 0);
}

// ---------------------------------------------------------------------------
// Fused fp32->bf16 prep: x (scale 1), wq (scale beta*log2e), wk (scale 1).
// Thread (0,0) also zeroes the energy accumulator (replaces a memset launch).
// ---------------------------------------------------------------------------
__global__ __launch_bounds__(256) void prep_kernel(const float* __restrict__ x,
                                                   const float* __restrict__ wq,
                                                   const float* __restrict__ wk,
                                                   const float* __restrict__ betas,
                                                   bf16* __restrict__ xb,
                                                   bf16* __restrict__ wqb,
                                                   bf16* __restrict__ wkb,
                                                   float* __restrict__ out) {
    const size_t NX = (size_t)BATCH * SEQ * EMBED;
    const size_t NW = (size_t)EMBED * EMBED;
    if (blockIdx.x == 0 && threadIdx.x == 0) out[0] = 0.f;
    size_t i4 = ((size_t)blockIdx.x * 256 + threadIdx.x) * 4;
    const float* src;
    bf16* dst;
    float sc;
    if (i4 < NX)            { src = x  + i4; dst = xb  + i4; sc = 1.0f; }
    else if (i4 < NX + NW)  { size_t i = i4 - NX; src = wq + i; dst = wqb + i;
                              sc = betas[i >> 16] * LOG2E; }   // 64*1024 elems/head
    else                    { size_t i = i4 - NX - NW; src = wk + i; dst = wkb + i; sc = 1.0f; }
    float4 v = *reinterpret_cast<const float4*>(src);
    bf16 o[4];
    o[0] = __float2bfloat16(v.x * sc);
    o[1] = __float2bfloat16(v.y * sc);
    o[2] = __float2bfloat16(v.z * sc);
    o[3] = __float2bfloat16(v.w * sc);
    *reinterpret_cast<bf16x4*>(dst) = *reinterpret_cast<const bf16x4*>(o);
}

// ---------------------------------------------------------------------------
// Fused q+k projection GEMM via MFMA. 128x128 tile, 512 threads (8 waves,
// 2x4 wave grid, 64x32 per wave) -> 16 waves/CU at grid 512 (was 8),
// doubling latency hiding vs the 256-thread version. global_load_lds 16B
// staging into linear LDS [128][64]. blockIdx.y < 8 -> wq/qout, else wk/kout.
// ---------------------------------------------------------------------------
__global__ __launch_bounds__(512) void proj_mfma(const bf16* __restrict__ xb,
                                                 const bf16* __restrict__ wqb,
                                                 const bf16* __restrict__ wkb,
                                                 bf16* __restrict__ qout,
                                                 bf16* __restrict__ kout) {
    __shared__ __align__(16) bf16 As[128][64];
    __shared__ __align__(16) bf16 Bs[128][64];
    const int tid  = threadIdx.x;
    const int lane = tid & 63;
    const int wave = tid >> 6;           // 0..7
    const int wr = wave >> 2, wc = wave & 3;   // 2 x 4
    const int m0 = blockIdx.x * 128;
    const bool isq = (blockIdx.y < 8);
    const int n0 = (blockIdx.y & 7) * 128;
    const bf16* wb = isq ? wqb : wkb;
    bf16* outb = isq ? qout : kout;
    const int srow = lane >> 3;          // row within 8-row chunk
    const int scol = (lane & 7) * 8;     // element col of this lane's 16B

    f32x4 acc[4][2] = {};

    for (int k0 = 0; k0 < EMBED; k0 += 64) {
        #pragma unroll
        for (int i = 0; i < 2; ++i) {
            int j = wave * 2 + i;        // chunk 0..15 (8 rows each)
            gload_lds16(&xb[(size_t)(m0 + j * 8 + srow) * EMBED + k0 + scol], &As[j * 8][0]);
            gload_lds16(&wb[(size_t)(n0 + j * 8 + srow) * EMBED + k0 + scol], &Bs[j * 8][0]);
        }
        __syncthreads();                 // drains vmcnt: staging complete
        #pragma unroll
        for (int ks = 0; ks < 2; ++ks) {
            bf16x8 af[4], bfr[2];
            #pragma unroll
            for (int a = 0; a < 4; ++a)
                af[a] = *reinterpret_cast<const bf16x8*>(&As[wr * 64 + a * 16 + (lane & 15)][ks * 32 + (lane >> 4) * 8]);
            #pragma unroll
            for (int b2 = 0; b2 < 2; ++b2)
                bfr[b2] = *reinterpret_cast<const bf16x8*>(&Bs[wc * 32 + b2 * 16 + (lane & 15)][ks * 32 + (lane >> 4) * 8]);
            #pragma unroll
            for (int a = 0; a < 4; ++a)
                #pragma unroll
                for (int b2 = 0; b2 < 2; ++b2)
                    acc[a][b2] = __builtin_amdgcn_mfma_f32_16x16x32_bf16(af[a], bfr[b2], acc[a][b2], 0, 0, 0);
        }
        __syncthreads();                 // reads done before next overwrite
    }
    #pragma unroll
    for (int a = 0; a < 4; ++a)
        #pragma unroll
        for (int b2 = 0; b2 < 2; ++b2)
            #pragma unroll
            for (int j = 0; j < 4; ++j) {
                int row = m0 + wr * 64 + a * 16 + (lane >> 4) * 4 + j;
                int col = n0 + wc * 32 + b2 * 16 + (lane & 15);
                outb[(size_t)row * EMBED + col] = __float2bfloat16(acc[a][b2][j]);
            }
}

// ---------------------------------------------------------------------------
// Masked exp-sum via 32x32x16 MFMA (fixed m=0: scores O(0.05), no overflow).
// One block = (b, h, 256 q rows, 512-k range); 4 waves own 64 q rows each
// (2 subtiles of 32). K staged 128 rows/iter in padded LDS [128][72].
// D layout (32x32): col = lane&31 -> q row (one q row per lane!);
// row = (reg&3)+8*(reg>>2)+4*(lane>>5) -> k row. Lane-local exp-sum, single
// shfl_xor(32) reduce. Diagonal handled in wave-uniform subtile branches.
// T5 setprio around MFMA bursts (4 independent blocks/CU at skewed phases).
// Partials (no atomics) to partial[row][KSPLIT].
// ---------------------------------------------------------------------------
__global__ __launch_bounds__(256, 4) void attn_sum_mfma(const bf16* __restrict__ q,
                                                        const bf16* __restrict__ k,
                                                        float* __restrict__ partial) {
    __shared__ __align__(16) bf16 Ks[128][72];
    const int tid  = threadIdx.x;
    const int lane = tid & 63;
    const int wave = tid >> 6;
    const int blk = blockIdx.x;          // (((b*16+h)*8)+qt)*KSPLIT + kt
    const int kt = blk & (KSPLIT - 1);
    const int qt = (blk >> 2) & 7;       // 8 q-tiles of 256 rows
    const int h  = (blk >> 5) & 15;
    const int b  = blk >> 9;
    const int n0 = qt * 256 + wave * 64; // this wave's 64 q rows
    const bf16* qbase = q + (size_t)(b * SEQ) * EMBED + h * HDIM;
    const bf16* kbase = k + (size_t)(b * SEQ) * EMBED + h * HDIM;

    // Q fragments: qf[qs][ks2]: row n0+qs*32+(lane&31), k = ks2*16+(lane>>5)*8
    bf16x8 qf[2][4];
    #pragma unroll
    for (int qs = 0; qs < 2; ++qs)
        #pragma unroll
        for (int ks2 = 0; ks2 < 4; ++ks2)
            qf[qs][ks2] = *reinterpret_cast<const bf16x8*>(
                &qbase[(size_t)(n0 + qs * 32 + (lane & 31)) * EMBED + ks2 * 16 + (lane >> 5) * 8]);

    f32x4 psv[2] = {};
    const int mbase = kt * (SEQ / KSPLIT);

    // staging: 128 rows x 64 cols per iter; 4x bf16x8 per thread
    const int sr = tid >> 3;             // base row 0..31 per chunk step of 32
    const int sc = (tid & 7) * 8;
    bf16x8 stg[4];
    #pragma unroll
    for (int c = 0; c < 4; ++c)
        stg[c] = *reinterpret_cast<const bf16x8*>(&kbase[(size_t)(mbase + c * 32 + sr) * EMBED + sc]);

    for (int it = 0; it < SEQ / KSPLIT / 128; ++it) {
        const int m0 = mbase + it * 128;
        __syncthreads();                 // prior Ks readers done
        #pragma unroll
        for (int c = 0; c < 4; ++c)
            *reinterpret_cast<bf16x8*>(&Ks[c * 32 + sr][sc]) = stg[c];
        __syncthreads();                 // Ks ready
        if (it + 1 < SEQ / KSPLIT / 128) {
            #pragma unroll
            for (int c = 0; c < 4; ++c)  // next tile; hides under compute (T14)
                stg[c] = *reinterpret_cast<const bf16x8*>(&kbase[(size_t)(m0 + 128 + c * 32 + sr) * EMBED + sc]);
        }

        #pragma unroll
        for (int t = 0; t < 4; ++t) {    // k subtiles of 32 rows
            bf16x8 kf[4];
            #pragma unroll
            for (int ks2 = 0; ks2 < 4; ++ks2)
                kf[ks2] = *reinterpret_cast<const bf16x8*>(
                    &Ks[t * 32 + (lane & 31)][ks2 * 16 + (lane >> 5) * 8]);
            #pragma unroll
            for (int qs = 0; qs < 2; ++qs) {
                f32x16 acc = {};
                __builtin_amdgcn_s_setprio(1);
                #pragma unroll
                for (int ks2 = 0; ks2 < 4; ++ks2)
                    acc = __builtin_amdgcn_mfma_f32_32x32x16_bf16(kf[ks2], qf[qs][ks2], acc, 0, 0, 0);
                __builtin_amdgcn_s_setprio(0);
                if ((m0 + t * 32) == (n0 + qs * 32)) {   // diagonal subtile
                    const int qcol = lane & 31;
                    #pragma unroll
                    for (int r = 0; r < 16; ++r) {
                        int crow = (r & 3) + 8 * (r >> 2) + 4 * (lane >> 5);
                        float e = fast_exp2(acc[r]);
                        psv[qs][r & 3] += (crow == qcol) ? 0.f : e;
                    }
                } else {
                    #pragma unroll
                    for (int r = 0; r < 16; ++r)
                        psv[qs][r & 3] += fast_exp2(acc[r]);
                }
            }
        }
    }

    #pragma unroll
    for (int qs = 0; qs < 2; ++qs) {
        float psum = (psv[qs][0] + psv[qs][1]) + (psv[qs][2] + psv[qs][3]);
        psum += __shfl_xor(psum, 32);    // lane l and l+32 hold same q row
        if (lane < 32) {
            size_t row = (size_t)(b * NHEADS + h) * SEQ + n0 + qs * 32 + lane;
            partial[row * KSPLIT + kt] = psum;
        }
    }
}

// ---------------------------------------------------------------------------
// lse = log(sum of KSPLIT partials) per row; energy = -sum(lse/beta)/(B*N).
// ---------------------------------------------------------------------------
__global__ __launch_bounds__(256) void finalize_kernel(const float* __restrict__ partial,
                                                       const float* __restrict__ betas,
                                                       float* __restrict__ out) {
    const int idx = blockIdx.x * 256 + threadIdx.x;    // 0..65535
    const float4 p = *reinterpret_cast<const float4*>(&partial[(size_t)idx * KSPLIT]);
    const int h = (idx >> 11) & 15;                    // idx = (b*16+h)*2048 + n
    float c = -logf(p.x + p.y + p.z + p.w) / (betas[h] * (float)(BATCH * SEQ));
    #pragma unroll
    for (int off = 1; off < 64; off <<= 1) c += __shfl_xor(c, off);
    __shared__ float ws[4];
    const int lane = threadIdx.x & 63, wave = threadIdx.x >> 6;
    if (lane == 0) ws[wave] = c;
    __syncthreads();
    if (threadIdx.x == 0) atomicAdd(out, ws[0] + ws[1] + ws[2] + ws[3]);
}

extern "C" void kernel_launch(void* const* d_in, const int* in_sizes, int n_in,
                              void* d_out, int out_size, void* d_ws, size_t ws_size,
                              hipStream_t stream) {
    const float* x     = (const float*)d_in[0];
    const float* wk    = (const float*)d_in[1];
    const float* wq    = (const float*)d_in[2];
    const float* betas = (const float*)d_in[3];
    float* out = (float*)d_out;

    const size_t NX = (size_t)BATCH * SEQ * EMBED;   // 4,194,304
    const size_t NW = (size_t)EMBED * EMBED;         // 1,048,576

    bf16* xb   = (bf16*)d_ws;                        // 8 MB
    bf16* wqb  = xb + NX;                            // 2 MB
    bf16* wkb  = wqb + NW;                           // 2 MB
    bf16* qb   = wkb + NW;                           // 8 MB
    bf16* kb   = qb + NX;                            // 8 MB
    float* prt = (float*)(kb + NX);                  // 1 MB: [B*H*SEQ][KSPLIT]

    prep_kernel<<<(int)((NX + 2 * NW) / 4 / 256), 256, 0, stream>>>(x, wq, wk, betas, xb, wqb, wkb, out);

    dim3 gproj(BATCH * SEQ / 128, 2 * EMBED / 128);  // (32, 16)
    proj_mfma<<<gproj, 512, 0, stream>>>(xb, wqb, wkb, qb, kb);

    attn_sum_mfma<<<BATCH * NHEADS * 8 * KSPLIT, 256, 0, stream>>>(qb, kb, prt);

    finalize_kernel<<<BATCH * NHEADS * SEQ / 256, 256, 0, stream>>>(prt, betas, out);
}